// Round 11
// baseline (306.706 us; speedup 1.0000x reference)
//
#include <hip/hip_runtime.h>
#include <hip/hip_fp16.h>
#include <hip/hip_cooperative_groups.h>

namespace cg = cooperative_groups;

// ---------- types ----------
typedef __attribute__((ext_vector_type(8))) _Float16 f16x8;
typedef __attribute__((ext_vector_type(4))) float f32x4;

typedef const __attribute__((address_space(1))) void gas_void;
typedef __attribute__((address_space(3))) void las_void;
typedef __attribute__((address_space(3))) const __half las_chalf;

__device__ __forceinline__ f16x8 ldsr(const __half* p) {
    f16x8 r;
    asm volatile("ds_read_b128 %0, %1" : "=v"(r) : "v"((las_chalf*)p));
    return r;
}

// ---------- threefry2x32, JAX PARTITIONABLE variant ----------
__device__ __forceinline__ uint32_t rotl32(uint32_t x, int d) { return (x << d) | (x >> (32 - d)); }

__device__ __forceinline__ bool keep_bit(uint32_t flat) {
    uint32_t x0 = 0u;
    uint32_t x1 = flat;
    const uint32_t ks0 = 0u, ks1 = 42u, ks2 = 0u ^ 42u ^ 0x1BD11BDAu;
    x0 += ks0; x1 += ks1;
#define TFR(r) { x0 += x1; x1 = rotl32(x1, r); x1 ^= x0; }
    TFR(13) TFR(15) TFR(26) TFR(6)   x0 += ks1; x1 += ks2 + 1u;
    TFR(17) TFR(29) TFR(16) TFR(24)  x0 += ks2; x1 += ks0 + 2u;
    TFR(13) TFR(15) TFR(26) TFR(6)   x0 += ks0; x1 += ks1 + 3u;
    TFR(17) TFR(29) TFR(16) TFR(24)  x0 += ks1; x1 += ks2 + 4u;
    TFR(13) TFR(15) TFR(26) TFR(6)   x0 += ks2; x1 += ks0 + 5u;
#undef TFR
    uint32_t bits = x0 ^ x1;
    float u = __uint_as_float((bits >> 9) | 0x3f800000u) - 1.0f;
    return u < 0.9f;
}

// ============================================================================
// 256x256 8-phase GEMM core (T2+T3+T4+T5). LD = row stride of A and B (equal
// in all our uses). K-loop byte-identical to the proven r6-r10 engine.
// ============================================================================
template <int LD>
__device__ __forceinline__ void gemm_core(const __half* __restrict__ A, const __half* __restrict__ B,
                                          int brow, int bcol, int k_lo, int NT,
                                          __half* smem, f32x4 (&acc)[8][4]) {
    const int tid = threadIdx.x;
    const int lane = tid & 63, wid = tid >> 6;
    const int wm = wid >> 2, wn = wid & 3;
    const int lane15 = lane & 15;
    const int kxor = (lane & 7) << 3;
    const int g16 = (lane >> 4) << 3;

    const int srow = (wid << 3) + (lane >> 3);
    const int scol = ((lane & 7) ^ ((lane >> 3) & 7)) << 3;

    auto stage_half = [&](const __half* G, int growbase, int kt, int buf, int mat, int half) {
        const __half* src = G + (size_t)(growbase + half * 128 + srow) * LD + kt * 64 + scol;
        __half* dst = &smem[buf * 32768 + mat * 16384 + (half * 128 + (wid << 3)) * 64];
        __builtin_amdgcn_global_load_lds((gas_void*)src, (las_void*)dst, 16, 0, 0);
        __builtin_amdgcn_global_load_lds((gas_void*)(src + (size_t)64 * LD),
                                         (las_void*)(dst + 64 * 64), 16, 0, 0);
    };

    f16x8 bfrag[2][4];

    stage_half(B, bcol, k_lo, 0, 1, 0);
    stage_half(B, bcol, k_lo, 0, 1, 1);
    stage_half(A, brow, k_lo, 0, 0, 0);
    stage_half(A, brow, k_lo, 0, 0, 1);
    if (NT > 1) {
        stage_half(B, bcol, k_lo + 1, 1, 1, 0);
        stage_half(B, bcol, k_lo + 1, 1, 1, 1);
    }

    for (int Tr = 0; Tr < NT; ++Tr) {
        const int Ta = k_lo + Tr;
        const int buf = Tr & 1;
        const __half* Abase = &smem[buf * 32768 + (wm * 128 + lane15) * 64];
        const __half* Bbase = &smem[buf * 32768 + 16384 + (wn * 64 + lane15) * 64];

        if (Tr < NT - 1) asm volatile("s_waitcnt vmcnt(4)" ::: "memory");
        else             asm volatile("s_waitcnt vmcnt(0)" ::: "memory");
        __builtin_amdgcn_s_barrier();

        {
#pragma unroll
            for (int kk = 0; kk < 2; ++kk)
#pragma unroll
                for (int n = 0; n < 4; ++n)
                    bfrag[kk][n] = ldsr(Bbase + (n * 16) * 64 + ((kk * 32 + g16) ^ kxor));
            f16x8 af[2][2];
#pragma unroll
            for (int mi = 0; mi < 2; ++mi)
#pragma unroll
                for (int kk = 0; kk < 2; ++kk)
                    af[mi][kk] = ldsr(Abase + (mi * 16) * 64 + ((kk * 32 + g16) ^ kxor));
            if (Tr + 1 < NT) stage_half(A, brow, Ta + 1, buf ^ 1, 0, 0);
            asm volatile("s_waitcnt lgkmcnt(0)" ::: "memory");
            __builtin_amdgcn_sched_barrier(0);
            __builtin_amdgcn_s_setprio(1);
#pragma unroll
            for (int mi = 0; mi < 2; ++mi)
#pragma unroll
                for (int n = 0; n < 4; ++n)
#pragma unroll
                    for (int kk = 0; kk < 2; ++kk)
                        acc[mi][n] = __builtin_amdgcn_mfma_f32_16x16x32_f16(
                            af[mi][kk], bfrag[kk][n], acc[mi][n], 0, 0, 0);
            __builtin_amdgcn_s_setprio(0);
            __builtin_amdgcn_s_barrier();
        }

#pragma unroll
        for (int p = 1; p < 4; ++p) {
            f16x8 af[2][2];
#pragma unroll
            for (int mi = 0; mi < 2; ++mi)
#pragma unroll
                for (int kk = 0; kk < 2; ++kk)
                    af[mi][kk] = ldsr(Abase + ((2 * p + mi) * 16) * 64 + ((kk * 32 + g16) ^ kxor));
            if (p == 1)      { if (Tr + 1 < NT) stage_half(A, brow, Ta + 1, buf ^ 1, 0, 1); }
            else if (p == 2) { if (Tr + 2 < NT) stage_half(B, bcol, Ta + 2, buf, 1, 0); }
            else             { if (Tr + 2 < NT) stage_half(B, bcol, Ta + 2, buf, 1, 1); }
            asm volatile("s_waitcnt lgkmcnt(0)" ::: "memory");
            __builtin_amdgcn_sched_barrier(0);
            __builtin_amdgcn_s_setprio(1);
#pragma unroll
            for (int mi = 0; mi < 2; ++mi)
#pragma unroll
                for (int n = 0; n < 4; ++n)
#pragma unroll
                    for (int kk = 0; kk < 2; ++kk)
                        acc[2 * p + mi][n] = __builtin_amdgcn_mfma_f32_16x16x32_f16(
                            af[mi][kk], bfrag[kk][n], acc[2 * p + mi][n], 0, 0, 0);
            __builtin_amdgcn_s_setprio(0);
            __builtin_amdgcn_s_barrier();
        }
    }
}

// ============================================================================
// Cooperative mega-kernel: cast -> {QKproj | VT} -> S -> softdrop -> PV -> merge
// 256 blocks x 512 threads, 128KB dynamic LDS, grid.sync() between stages.
// ============================================================================
__global__ __launch_bounds__(512, 2)
void mega_k(const float* __restrict__ x, const float* __restrict__ wq,
            const float* __restrict__ wk, const float* __restrict__ wv,
            __half* __restrict__ xb, __half* __restrict__ wqkv,
            __half* __restrict__ QK, __half* __restrict__ VT,
            __half* __restrict__ SP, float* __restrict__ Lr,
            float* __restrict__ out,
            float* __restrict__ P1, float* __restrict__ P2, float* __restrict__ P3) {
    cg::grid_group grid = cg::this_grid();
    extern __shared__ __half smem[];

    const int id = blockIdx.x;
    const int tid = threadIdx.x;
    const int role = (id & 7) * 32 + (id >> 3);   // XCD-aware bijective role map
    const int gtid = id * 512 + tid;

    // ---- S0: cast all inputs f32 -> f16 ----
    {
        for (int t = gtid; t < 524288; t += 131072) {       // x: 4096x1024
            const size_t i = (size_t)t * 8;
            float4 a = *(const float4*)(x + i);
            float4 c = *(const float4*)(x + i + 4);
            __half2 h[4] = { __floats2half2_rn(a.x, a.y), __floats2half2_rn(a.z, a.w),
                             __floats2half2_rn(c.x, c.y), __floats2half2_rn(c.z, c.w) };
            *(int4*)(xb + i) = *(int4*)h;
        }
        for (int t = gtid; t < 393216; t += 131072) {       // wq|wk|wv: 3x 1024x1024
            const size_t i = (size_t)t * 8;
            const int w = (int)(i >> 20);
            const float* src = w == 0 ? wq : (w == 1 ? wk : wv);
            const size_t off = i & 1048575u;
            float4 a = *(const float4*)(src + off);
            float4 c = *(const float4*)(src + off + 4);
            __half2 h[4] = { __floats2half2_rn(a.x, a.y), __floats2half2_rn(a.z, a.w),
                             __floats2half2_rn(c.x, c.y), __floats2half2_rn(c.z, c.w) };
            *(int4*)(wqkv + i) = *(int4*)h;
        }
    }
    grid.sync();

    const int lane = tid & 63, wid = tid >> 6;
    const int wm = wid >> 2, wn = wid & 3;
    const int lane15 = lane & 15;
    const int r0 = (lane >> 4) << 2;

    // ---- S1: QK projection (roles 0..127) + VT = wv @ x^T (roles 128..191) ----
    if (role < 192) {
        f32x4 acc[8][4] = {};
        if (role < 128) {
            const int bi = role >> 3, bj = role & 7;
            gemm_core<1024>(xb, wqkv, bi * 256, bj * 256, 0, 16, smem, acc);
#pragma unroll
            for (int m = 0; m < 8; ++m)
#pragma unroll
                for (int n = 0; n < 4; ++n) {
                    const int col = bj * 256 + wn * 64 + n * 16 + lane15;
#pragma unroll
                    for (int r = 0; r < 4; ++r) {
                        const int row = bi * 256 + wm * 128 + m * 16 + r0 + r;
                        QK[(size_t)row * 2048 + col] = __float2half(acc[m][n][r]);
                    }
                }
        } else {
            const int s2 = role - 128;
            const int bi = s2 >> 4, bj = s2 & 15;
            gemm_core<1024>(wqkv + 2097152, xb, bi * 256, bj * 256, 0, 16, smem, acc);
#pragma unroll
            for (int m = 0; m < 8; ++m)
#pragma unroll
                for (int n = 0; n < 4; ++n) {
                    const int col = bj * 256 + wn * 64 + n * 16 + lane15;
#pragma unroll
                    for (int r = 0; r < 4; ++r) {
                        const int row = bi * 256 + wm * 128 + m * 16 + r0 + r;
                        VT[(size_t)row * 4096 + col] = __float2half(acc[m][n][r]);
                    }
                }
        }
    }
    grid.sync();

    // ---- S2: S = Q @ K^T * (1/32), triangular roles 0..135 ----
    if (role < 136) {
        int b = (int)((sqrtf(8.0f * role + 1.0f) - 1.0f) * 0.5f);
        while ((b + 1) * (b + 2) / 2 <= role) ++b;
        while (b * (b + 1) / 2 > role) --b;
        const int bi = b, bj = role - b * (b + 1) / 2;
        f32x4 acc[8][4] = {};
        gemm_core<2048>(QK, QK + 1024, bi * 256, bj * 256, 0, 16, smem, acc);
#pragma unroll
        for (int m = 0; m < 8; ++m)
#pragma unroll
            for (int n = 0; n < 4; ++n) {
                const int col = bj * 256 + wn * 64 + n * 16 + lane15;
#pragma unroll
                for (int r = 0; r < 4; ++r) {
                    const int row = bi * 256 + wm * 128 + m * 16 + r0 + r;
                    SP[(size_t)row * 4096 + col] = __float2half(acc[m][n][r] * 0.03125f);
                }
            }
    }
    grid.sync();

    // ---- S3: softdrop: P' = keep * exp(S), Lr[row] = sum exp(S); band-zero ----
    {
        float* ls = (float*)smem;
        for (int i = id; i < 4096; i += 256) {
            const int len = i + 1;
            __half* row = SP + (size_t)i * 4096;

            float l = 0.f;
            const int len8 = len & ~7;
            for (int j = tid * 8; j < len8; j += 4096) {
                int4 pk = *(const int4*)(row + j);
                const __half* hp = (const __half*)&pk;
                __half o8[8];
                const uint32_t base = (uint32_t)i * 4096u + (uint32_t)j;
#pragma unroll
                for (int q = 0; q < 8; ++q) {
                    float e = __expf(__half2float(hp[q]));
                    l += e;
                    o8[q] = keep_bit(base + q) ? __float2half(e) : __float2half(0.0f);
                }
                *(int4*)(row + j) = *(int4*)o8;
            }
            for (int j = len8 + tid; j < len; j += 512) {
                float e = __expf(__half2float(row[j]));
                l += e;
                row[j] = keep_bit((uint32_t)i * 4096u + (uint32_t)j) ? __float2half(e)
                                                                     : __float2half(0.0f);
            }

            for (int off = 1; off < 64; off <<= 1) l += __shfl_xor(l, off);
            if (lane == 0) ls[wid] = l;
            __syncthreads();
            if (tid == 0) {
                float s = 0.f;
#pragma unroll
                for (int w = 0; w < 8; ++w) s += ls[w];
                Lr[i] = s;
            }

            const int zlim = ((i >> 8) << 8) + 256;
            const int za = (len + 7) & ~7;
            for (int j = len + tid; j < min(za, zlim); j += 512) row[j] = __float2half(0.0f);
            const int4 z = {0, 0, 0, 0};
            for (int j = za + tid * 8; j < zlim; j += 4096) *(int4*)(row + j) = z;
            __syncthreads();
        }
    }
    grid.sync();

    // ---- S4: PV = P' @ VT^T, balanced causal split-K, roles 0..159 ----
    if (role < 160) {
        const int bj = role / 40;
        const int xr = role - 40 * bj;
        int bi, c;
        if (xr < 4)       { bi = xr;                     c = 0; }
        else if (xr < 12) { bi = 4  + ((xr - 4) >> 1);   c = (xr - 4) & 1; }
        else if (xr < 24) { bi = 8  + (xr - 12) / 3;     c = (xr - 12) % 3; }
        else              { bi = 12 + ((xr - 24) >> 2);  c = (xr - 24) & 3; }
        const int full = 4 * (bi + 1);
        const int k_lo = c * 16;
        const int NT = min(full - k_lo, 16);

        f32x4 acc[8][4] = {};
        gemm_core<4096>(SP, VT, bi * 256, bj * 256, k_lo, NT, smem, acc);

        float* Ct = out;
        if (c == 1) Ct = P1; else if (c == 2) Ct = P2; else if (c == 3) Ct = P3;
        const bool doScale = (c == 0) && (bi < 4);
#pragma unroll
        for (int m = 0; m < 8; ++m)
#pragma unroll
            for (int r = 0; r < 4; ++r) {
                const int row = bi * 256 + wm * 128 + m * 16 + r0 + r;
                const float inv = doScale ? 1.0f / (0.9f * Lr[row]) : 1.0f;
#pragma unroll
                for (int n = 0; n < 4; ++n) {
                    const int col = bj * 256 + wn * 64 + n * 16 + lane15;
                    Ct[(size_t)row * 1024 + col] = acc[m][n][r] * inv;
                }
            }
    }
    grid.sync();

    // ---- S5: merge split-K partials + scale rows >= 1024 ----
    for (int it = 0; it < 6; ++it) {
        const int row = 1024 + id * 12 + it * 2 + (tid >> 8);
        const int cv = tid & 255;
        const float inv = 1.0f / (0.9f * Lr[row]);
        const size_t o = (size_t)row * 1024 + cv * 4;
        float4 s = *(float4*)(out + o);
        float4 a = *(const float4*)(P1 + o);
        s.x += a.x; s.y += a.y; s.z += a.z; s.w += a.w;
        if (row >= 2048) {
            float4 b2 = *(const float4*)(P2 + o);
            s.x += b2.x; s.y += b2.y; s.z += b2.z; s.w += b2.w;
        }
        if (row >= 3072) {
            float4 d = *(const float4*)(P3 + o);
            s.x += d.x; s.y += d.y; s.z += d.z; s.w += d.w;
        }
        s.x *= inv; s.y *= inv; s.z *= inv; s.w *= inv;
        *(float4*)(out + o) = s;
    }
}

// ============================================================================
// FALLBACK: round-10 6-dispatch path (unchanged), used if cooperative launch fails
// ============================================================================
__global__ __launch_bounds__(256) void cast_all_k(const float* __restrict__ x,
                                                  const float* __restrict__ wq,
                                                  const float* __restrict__ wk,
                                                  const float* __restrict__ wv,
                                                  __half* __restrict__ xb,
                                                  __half* __restrict__ wqkv) {
    const int b = blockIdx.x;
    const float* src;
    __half* dst;
    size_t i;
    if (b < 2048) {
        src = x; dst = xb;
        i = ((size_t)b * 256 + threadIdx.x) * 8;
    } else {
        const int w = (b - 2048) >> 9;
        src = w == 0 ? wq : (w == 1 ? wk : wv);
        dst = wqkv + (size_t)w * 1048576;
        i = (((size_t)((b - 2048) & 511)) * 256 + threadIdx.x) * 8;
    }
    float4 a = *(const float4*)(src + i);
    float4 c = *(const float4*)(src + i + 4);
    __half2 h[4] = { __floats2half2_rn(a.x, a.y), __floats2half2_rn(a.z, a.w),
                     __floats2half2_rn(c.x, c.y), __floats2half2_rn(c.z, c.w) };
    *(int4*)(dst + i) = *(int4*)h;
}

template <int MODE>
__global__ __launch_bounds__(512, 2)
void gemm256(const __half* __restrict__ pA, const __half* __restrict__ pB,
             void* __restrict__ pC, void* __restrict__ pC2,
             float* __restrict__ P1, float* __restrict__ P2, float* __restrict__ P3,
             const float* __restrict__ Lr) {
    int bi, bj, c = 0, k_lo = 0, NT = 16;
    bool isVT = false;
    if constexpr (MODE == 0) {
        const int id = blockIdx.x;
        const int sw = (id & 7) * 24 + (id >> 3);
        if (sw < 128) { bi = sw >> 3; bj = sw & 7; }
        else          { int s2 = sw - 128; bi = s2 >> 4; bj = s2 & 15; isVT = true; }
    } else if constexpr (MODE == 1) {
        const int id = blockIdx.x;
        const int sw = (id & 7) * 17 + (id >> 3);
        int b = (int)((sqrtf(8.0f * sw + 1.0f) - 1.0f) * 0.5f);
        while ((b + 1) * (b + 2) / 2 <= sw) ++b;
        while (b * (b + 1) / 2 > sw) --b;
        bi = b; bj = sw - b * (b + 1) / 2;
    } else {
        const int id = blockIdx.x;
        const int sw = (id & 7) * 20 + (id >> 3);
        bj = sw / 40;
        const int xr = sw - 40 * bj;
        if (xr < 4)       { bi = xr;                     c = 0; }
        else if (xr < 12) { bi = 4  + ((xr - 4) >> 1);   c = (xr - 4) & 1; }
        else if (xr < 24) { bi = 8  + (xr - 12) / 3;     c = (xr - 12) % 3; }
        else              { bi = 12 + ((xr - 24) >> 2);  c = (xr - 24) & 3; }
        const int full = 4 * (bi + 1);
        k_lo = c * 16;
        NT = min(full - k_lo, 16);
    }

    const __half* A = pA;
    const __half* B = pB;
    if constexpr (MODE == 0) {
        if (isVT) { A = pB + 2097152; B = pA; }
    }

    extern __shared__ __half smem[];
    f32x4 acc[8][4] = {};
    constexpr int LD = (MODE == 0) ? 1024 : (MODE == 1 ? 2048 : 4096);
    gemm_core<LD>(A, B, bi * 256, bj * 256, k_lo, NT, smem, acc);

    const int tid = threadIdx.x;
    const int lane = tid & 63, wid = tid >> 6;
    const int wm = wid >> 2, wn = wid & 3;
    const int lane15 = lane & 15;
    const int r0 = (lane >> 4) << 2;

    if constexpr (MODE == 2) {
        float* Ct = (float*)pC;
        if (c == 1) Ct = P1; else if (c == 2) Ct = P2; else if (c == 3) Ct = P3;
        const bool doScale = (c == 0) && (bi < 4);
#pragma unroll
        for (int m = 0; m < 8; ++m)
#pragma unroll
            for (int r = 0; r < 4; ++r) {
                const int row = bi * 256 + wm * 128 + m * 16 + r0 + r;
                const float inv = doScale ? 1.0f / (0.9f * Lr[row]) : 1.0f;
#pragma unroll
                for (int n = 0; n < 4; ++n) {
                    const int col = bj * 256 + wn * 64 + n * 16 + lane15;
                    Ct[(size_t)row * 1024 + col] = acc[m][n][r] * inv;
                }
            }
    } else {
        __half* Ct = (__half*)pC;
        int ldc = (MODE == 1) ? 4096 : 2048;
        float scl = (MODE == 1) ? 0.03125f : 1.0f;
        if constexpr (MODE == 0) {
            if (isVT) { Ct = (__half*)pC2; ldc = 4096; }
        }
#pragma unroll
        for (int m = 0; m < 8; ++m)
#pragma unroll
            for (int n = 0; n < 4; ++n) {
                const int col = bj * 256 + wn * 64 + n * 16 + lane15;
#pragma unroll
                for (int r = 0; r < 4; ++r) {
                    const int row = bi * 256 + wm * 128 + m * 16 + r0 + r;
                    Ct[(size_t)row * ldc + col] = __float2half(acc[m][n][r] * scl);
                }
            }
    }
}

__global__ __launch_bounds__(256) void pv_scale_reduce_k(float* __restrict__ out,
                                                         const float* __restrict__ P1,
                                                         const float* __restrict__ P2,
                                                         const float* __restrict__ P3,
                                                         const float* __restrict__ L) {
    const int row = 1024 + blockIdx.x;
    const float inv = 1.0f / (0.9f * L[row]);
    const size_t o = (size_t)row * 1024 + threadIdx.x * 4;
    float4 s = *(float4*)(out + o);
    float4 a = *(const float4*)(P1 + o);
    s.x += a.x; s.y += a.y; s.z += a.z; s.w += a.w;
    if (row >= 2048) {
        float4 b = *(const float4*)(P2 + o);
        s.x += b.x; s.y += b.y; s.z += b.z; s.w += b.w;
    }
    if (row >= 3072) {
        float4 d = *(const float4*)(P3 + o);
        s.x += d.x; s.y += d.y; s.z += d.z; s.w += d.w;
    }
    s.x *= inv; s.y *= inv; s.z *= inv; s.w *= inv;
    *(float4*)(out + o) = s;
}

__global__ __launch_bounds__(256) void softdrop_k(__half* __restrict__ SP,
                                                  float* __restrict__ L, int N) {
    const int i = blockIdx.x;
    const int tid = threadIdx.x;
    const int len = i + 1;
    __half* row = SP + (size_t)i * N;

    float l = 0.f;
    const int len8 = len & ~7;
    for (int j = tid * 8; j < len8; j += 2048) {
        int4 pk = *(const int4*)(row + j);
        const __half* hp = (const __half*)&pk;
        __half o8[8];
        const uint32_t base = (uint32_t)i * 4096u + (uint32_t)j;
#pragma unroll
        for (int q = 0; q < 8; ++q) {
            float e = __expf(__half2float(hp[q]));
            l += e;
            o8[q] = keep_bit(base + q) ? __float2half(e) : __float2half(0.0f);
        }
        *(int4*)(row + j) = *(int4*)o8;
    }
    for (int j = len8 + tid; j < len; j += 256) {
        float e = __expf(__half2float(row[j]));
        l += e;
        row[j] = keep_bit((uint32_t)i * 4096u + (uint32_t)j) ? __float2half(e) : __float2half(0.0f);
    }

    for (int off = 1; off < 64; off <<= 1) l += __shfl_xor(l, off);
    __shared__ float ls[4];
    if ((tid & 63) == 0) ls[tid >> 6] = l;
    __syncthreads();
    if (tid == 0) L[i] = ls[0] + ls[1] + ls[2] + ls[3];

    const int zlim = ((i >> 8) << 8) + 256;
    const int za = (len + 7) & ~7;
    for (int j = len + tid; j < min(za, zlim); j += 256) row[j] = __float2half(0.0f);
    const int4 z = {0, 0, 0, 0};
    for (int j = za + tid * 8; j < zlim; j += 2048) *(int4*)(row + j) = z;
}

// ---------- launch ----------
extern "C" void kernel_launch(void* const* d_in, const int* in_sizes, int n_in,
                              void* d_out, int out_size, void* d_ws, size_t ws_size,
                              hipStream_t stream) {
    const float* x  = (const float*)d_in[0];
    const float* wq = (const float*)d_in[1];
    const float* wk = (const float*)d_in[2];
    const float* wv = (const float*)d_in[3];
    float* out = (float*)d_out;
    char* ws = (char*)d_ws;

    const int N = 4096;

    __half* xb   = (__half*)(ws + 0);         // 4096x1024   (8 MB)
    __half* wqkv = (__half*)(ws + 8388608);   // 3072x1024   (6 MB)
    __half* QK   = (__half*)(ws + 14680064);  // 4096x2048   (16 MB), ld=2048
    __half* VT   = (__half*)(ws + 31457280);  // 1024x4096   (8 MB),  ld=4096
    __half* SP   = (__half*)(ws + 48234496);  // 4096x4096   (32 MB)
    float*  Lr   = (float*)(ws + 81788928);   // 4096 f32    (16 KB)

    float* P1 = (float*)(ws + 14680064) - (size_t)1024 * 1024;
    float* P3 = (float*)(ws + 27262976) - (size_t)3072 * 1024;
    float* P2 = (float*)(ws + 39845888) - (size_t)2048 * 1024;

    (void)hipFuncSetAttribute((const void*)mega_k, hipFuncAttributeMaxDynamicSharedMemorySize, 131072);

    void* args[] = { (void*)&x, (void*)&wq, (void*)&wk, (void*)&wv,
                     (void*)&xb, (void*)&wqkv, (void*)&QK, (void*)&VT,
                     (void*)&SP, (void*)&Lr, (void*)&out,
                     (void*)&P1, (void*)&P2, (void*)&P3 };
    hipError_t err = hipLaunchCooperativeKernel((const void*)mega_k, dim3(256), dim3(512),
                                                args, 131072, stream);
    if (err == hipSuccess) return;

    // ---- fallback: round-10 six-dispatch path ----
    __half* Q = QK;
    __half* K = QK + 1024;

    auto* g0 = gemm256<0>;
    auto* g1 = gemm256<1>;
    auto* g2 = gemm256<2>;
    (void)hipFuncSetAttribute((const void*)g0, hipFuncAttributeMaxDynamicSharedMemorySize, 131072);
    (void)hipFuncSetAttribute((const void*)g1, hipFuncAttributeMaxDynamicSharedMemorySize, 131072);
    (void)hipFuncSetAttribute((const void*)g2, hipFuncAttributeMaxDynamicSharedMemorySize, 131072);

    cast_all_k<<<3584, 256, 0, stream>>>(x, wq, wk, wv, xb, wqkv);
    g0<<<192, 512, 131072, stream>>>(xb, wqkv, QK, VT, nullptr, nullptr, nullptr, nullptr);
    g1<<<136, 512, 131072, stream>>>(Q, K, SP, nullptr, nullptr, nullptr, nullptr, nullptr);
    softdrop_k<<<N, 256, 0, stream>>>(SP, Lr, N);
    g2<<<160, 512, 131072, stream>>>(SP, VT, out, nullptr, P1, P2, P3, Lr);
    pv_scale_reduce_k<<<3072, 256, 0, stream>>>(out, P1, P2, P3, Lr);
}

// Round 12
// 139.310 us; speedup vs baseline: 2.2016x; 2.2016x over previous
//
#include <hip/hip_runtime.h>
#include <hip/hip_fp16.h>

// ---------- types ----------
typedef __attribute__((ext_vector_type(8))) _Float16 f16x8;
typedef __attribute__((ext_vector_type(4))) float f32x4;

typedef const __attribute__((address_space(1))) void gas_void;
typedef __attribute__((address_space(3))) void las_void;
typedef __attribute__((address_space(3))) const __half las_chalf;

// asm ds_read_b128: opaque to the compiler's waitcnt pass (we manage lgkmcnt)
__device__ __forceinline__ f16x8 ldsr(const __half* p) {
    f16x8 r;
    asm volatile("ds_read_b128 %0, %1" : "=v"(r) : "v"((las_chalf*)p));
    return r;
}

// ---------- all input casts f32 -> f16 in one dispatch (grid 3584) ----------
__global__ __launch_bounds__(256) void cast_all_k(const float* __restrict__ x,
                                                  const float* __restrict__ wq,
                                                  const float* __restrict__ wk,
                                                  const float* __restrict__ wv,
                                                  __half* __restrict__ xb,
                                                  __half* __restrict__ wqkv) {
    const int b = blockIdx.x;
    const float* src;
    __half* dst;
    size_t i;
    if (b < 2048) {
        src = x; dst = xb;
        i = ((size_t)b * 256 + threadIdx.x) * 8;
    } else {
        const int w = (b - 2048) >> 9;
        src = w == 0 ? wq : (w == 1 ? wk : wv);
        dst = wqkv + (size_t)w * 1048576;
        i = (((size_t)((b - 2048) & 511)) * 256 + threadIdx.x) * 8;
    }
    float4 a = *(const float4*)(src + i);
    float4 c = *(const float4*)(src + i + 4);
    __half2 h[4] = { __floats2half2_rn(a.x, a.y), __floats2half2_rn(a.z, a.w),
                     __floats2half2_rn(c.x, c.y), __floats2half2_rn(c.z, c.w) };
    *(int4*)(dst + i) = *(int4*)h;
}

// ============================================================================
// 256x256 8-phase GEMM engine (T1+T2+T3+T4+T5), C = scale * A @ B^T, f16 in.
// 8 waves (2M x 4N), BK=64, LDS 128KB dynamic: [buf(2)][mat(2)][256][64] f16.
// MODE 0 (QKVT): grid 192. sw<128: QK proj (ld 2048); sw>=128: VT = wv @ x^T.
// MODE 1 (S)   : grid 136, triangular decode.
// MODE 2 (PV)  : grid 196, balanced causal split-K, chunks <=13 tiles;
//                chunk 0 -> out (rows<768 scaled), chunks 1..4 -> f16 PH1..PH4.
// ============================================================================
template <int MODE>
__global__ __launch_bounds__(512, 2)
void gemm256(const __half* __restrict__ pA, const __half* __restrict__ pB,
             void* __restrict__ pC, void* __restrict__ pC2,
             __half* __restrict__ PH1, __half* __restrict__ PH2,
             __half* __restrict__ PH3, __half* __restrict__ PH4,
             const float* __restrict__ Lr) {
    constexpr int LD = (MODE == 0) ? 1024 : (MODE == 1 ? 2048 : 4096);

    int bi, bj, c = 0, k_lo = 0, NT = 16;
    bool isVT = false;
    if constexpr (MODE == 0) {
        const int id = blockIdx.x;
        const int sw = (id & 7) * 24 + (id >> 3);          // 192 = 8*24, bijective
        if (sw < 128) { bi = sw >> 3; bj = sw & 7; }
        else          { int s2 = sw - 128; bi = s2 >> 4; bj = s2 & 15; isVT = true; }
    } else if constexpr (MODE == 1) {
        const int id = blockIdx.x;
        const int sw = (id & 7) * 17 + (id >> 3);          // 136 = 8*17
        int b = (int)((sqrtf(8.0f * sw + 1.0f) - 1.0f) * 0.5f);
        while ((b + 1) * (b + 2) / 2 <= sw) ++b;
        while (b * (b + 1) / 2 > sw) --b;
        bi = b; bj = sw - b * (b + 1) / 2;
    } else {
        // m204 bijective XCD swizzle over 196 blocks (196 = 4*25 + 4*24)
        const int id = blockIdx.x;
        const int xcd = id & 7;
        const int sw = (xcd < 4 ? xcd * 25 : 100 + (xcd - 4) * 24) + (id >> 3);
        bj = sw / 49;
        int x = sw - 49 * bj;
        int nch = 1;
        for (bi = 0; bi < 16; ++bi) {
            nch = (4 * (bi + 1) + 12) / 13;
            if (x < nch) { c = x; break; }
            x -= nch;
        }
        const int full = 4 * (bi + 1);
        k_lo = c * 13;
        NT = min(full - k_lo, 13);
    }

    const __half* A = pA;
    const __half* B = pB;
    if constexpr (MODE == 0) {
        if (isVT) { A = pB + 2097152; B = pA; }   // A = wv (rows 2048.. of wqkv), B = x
    }

    const int brow = bi * 256, bcol = bj * 256;
    const int tid = threadIdx.x;
    const int lane = tid & 63, wid = tid >> 6;
    const int wm = wid >> 2, wn = wid & 3;
    const int lane15 = lane & 15;
    const int kxor = (lane & 7) << 3;
    const int g16 = (lane >> 4) << 3;

    extern __shared__ __half smem[];  // [2][2][256*64]

    const int srow = (wid << 3) + (lane >> 3);                 // 0..63
    const int scol = ((lane & 7) ^ ((lane >> 3) & 7)) << 3;    // swizzled source col

    auto stage_half = [&](const __half* G, int growbase, int kt, int buf, int mat, int half) {
        const __half* src = G + (size_t)(growbase + half * 128 + srow) * LD + kt * 64 + scol;
        __half* dst = &smem[buf * 32768 + mat * 16384 + (half * 128 + (wid << 3)) * 64];
        __builtin_amdgcn_global_load_lds((gas_void*)src, (las_void*)dst, 16, 0, 0);
        __builtin_amdgcn_global_load_lds((gas_void*)(src + (size_t)64 * LD),
                                         (las_void*)(dst + 64 * 64), 16, 0, 0);
    };

    f32x4 acc[8][4] = {};
    f16x8 bfrag[2][4];

    // prologue: tile k_lo {Ba,Bb,Aa,Ab} + tile k_lo+1 {Ba,Bb}
    stage_half(B, bcol, k_lo, 0, 1, 0);
    stage_half(B, bcol, k_lo, 0, 1, 1);
    stage_half(A, brow, k_lo, 0, 0, 0);
    stage_half(A, brow, k_lo, 0, 0, 1);
    if (NT > 1) {
        stage_half(B, bcol, k_lo + 1, 1, 1, 0);
        stage_half(B, bcol, k_lo + 1, 1, 1, 1);
    }

    for (int Tr = 0; Tr < NT; ++Tr) {
        const int Ta = k_lo + Tr;
        const int buf = Tr & 1;
        const __half* Abase = &smem[buf * 32768 + (wm * 128 + lane15) * 64];
        const __half* Bbase = &smem[buf * 32768 + 16384 + (wn * 64 + lane15) * 64];

        // ---- phase 0 ----
        if (Tr < NT - 1) asm volatile("s_waitcnt vmcnt(4)" ::: "memory");
        else             asm volatile("s_waitcnt vmcnt(0)" ::: "memory");
        __builtin_amdgcn_s_barrier();   // tile Tr fully resident for all waves

        {
#pragma unroll
            for (int kk = 0; kk < 2; ++kk)
#pragma unroll
                for (int n = 0; n < 4; ++n)
                    bfrag[kk][n] = ldsr(Bbase + (n * 16) * 64 + ((kk * 32 + g16) ^ kxor));
            f16x8 af[2][2];
#pragma unroll
            for (int mi = 0; mi < 2; ++mi)
#pragma unroll
                for (int kk = 0; kk < 2; ++kk)
                    af[mi][kk] = ldsr(Abase + (mi * 16) * 64 + ((kk * 32 + g16) ^ kxor));
            if (Tr + 1 < NT) stage_half(A, brow, Ta + 1, buf ^ 1, 0, 0);
            asm volatile("s_waitcnt lgkmcnt(0)" ::: "memory");
            __builtin_amdgcn_sched_barrier(0);
            __builtin_amdgcn_s_setprio(1);
#pragma unroll
            for (int mi = 0; mi < 2; ++mi)
#pragma unroll
                for (int n = 0; n < 4; ++n)
#pragma unroll
                    for (int kk = 0; kk < 2; ++kk)
                        acc[mi][n] = __builtin_amdgcn_mfma_f32_16x16x32_f16(
                            af[mi][kk], bfrag[kk][n], acc[mi][n], 0, 0, 0);
            __builtin_amdgcn_s_setprio(0);
            __builtin_amdgcn_s_barrier();
        }

        // ---- phases 1..3 ----
#pragma unroll
        for (int p = 1; p < 4; ++p) {
            f16x8 af[2][2];
#pragma unroll
            for (int mi = 0; mi < 2; ++mi)
#pragma unroll
                for (int kk = 0; kk < 2; ++kk)
                    af[mi][kk] = ldsr(Abase + ((2 * p + mi) * 16) * 64 + ((kk * 32 + g16) ^ kxor));
            if (p == 1)      { if (Tr + 1 < NT) stage_half(A, brow, Ta + 1, buf ^ 1, 0, 1); }
            else if (p == 2) { if (Tr + 2 < NT) stage_half(B, bcol, Ta + 2, buf, 1, 0); }
            else             { if (Tr + 2 < NT) stage_half(B, bcol, Ta + 2, buf, 1, 1); }
            asm volatile("s_waitcnt lgkmcnt(0)" ::: "memory");
            __builtin_amdgcn_sched_barrier(0);
            __builtin_amdgcn_s_setprio(1);
#pragma unroll
            for (int mi = 0; mi < 2; ++mi)
#pragma unroll
                for (int n = 0; n < 4; ++n)
#pragma unroll
                    for (int kk = 0; kk < 2; ++kk)
                        acc[2 * p + mi][n] = __builtin_amdgcn_mfma_f32_16x16x32_f16(
                            af[mi][kk], bfrag[kk][n], acc[2 * p + mi][n], 0, 0, 0);
            __builtin_amdgcn_s_setprio(0);
            __builtin_amdgcn_s_barrier();
        }
    }

    // ---- epilogue ----
    const int r0 = (lane >> 4) << 2;
    if constexpr (MODE == 2) {
        if (c == 0) {
            float* Ct = (float*)pC;
            const bool doScale = (4 * (bi + 1) <= 13);   // single-chunk rows (bi<=2)
#pragma unroll
            for (int m = 0; m < 8; ++m)
#pragma unroll
                for (int r = 0; r < 4; ++r) {
                    const int row = brow + wm * 128 + m * 16 + r0 + r;
                    const float inv = doScale ? 1.0f / (0.9f * Lr[row]) : 1.0f;
#pragma unroll
                    for (int n = 0; n < 4; ++n) {
                        const int col = bcol + wn * 64 + n * 16 + lane15;
                        Ct[(size_t)row * 1024 + col] = acc[m][n][r] * inv;
                    }
                }
        } else {
            __half* Ph = (c == 1) ? PH1 : (c == 2 ? PH2 : (c == 3 ? PH3 : PH4));
#pragma unroll
            for (int m = 0; m < 8; ++m)
#pragma unroll
                for (int n = 0; n < 4; ++n) {
                    const int col = bcol + wn * 64 + n * 16 + lane15;
#pragma unroll
                    for (int r = 0; r < 4; ++r) {
                        const int row = brow + wm * 128 + m * 16 + r0 + r;
                        Ph[(size_t)row * 1024 + col] = __float2half(acc[m][n][r]);
                    }
                }
        }
    } else {
        __half* Ct = (__half*)pC;
        int ldc = (MODE == 1) ? 4096 : 2048;
        const float scl = (MODE == 1) ? 0.03125f : 1.0f;
        if constexpr (MODE == 0) {
            if (isVT) { Ct = (__half*)pC2; ldc = 4096; }
        }
#pragma unroll
        for (int m = 0; m < 8; ++m)
#pragma unroll
            for (int n = 0; n < 4; ++n) {
                const int col = bcol + wn * 64 + n * 16 + lane15;
#pragma unroll
                for (int r = 0; r < 4; ++r) {
                    const int row = brow + wm * 128 + m * 16 + r0 + r;
                    Ct[(size_t)row * ldc + col] = __float2half(acc[m][n][r] * scl);
                }
            }
    }
}

// ---------- split-K merge (rows >= 768) + deferred softmax scaling ----------
__global__ __launch_bounds__(256) void pv_merge_k(float* __restrict__ out,
                                                  const __half* __restrict__ PH1,
                                                  const __half* __restrict__ PH2,
                                                  const __half* __restrict__ PH3,
                                                  const __half* __restrict__ PH4,
                                                  const float* __restrict__ L) {
    const int row = 768 + blockIdx.x;
    const int bi = row >> 8;
    const int nch = (4 * (bi + 1) + 12) / 13;
    const float inv = 1.0f / (0.9f * L[row]);
    const size_t o = (size_t)row * 1024 + threadIdx.x * 4;
    float4 s = *(float4*)(out + o);
    const __half* planes[4] = { PH1, PH2, PH3, PH4 };
#pragma unroll 4
    for (int cc = 1; cc < nch; ++cc) {
        const __half2* p2 = (const __half2*)(planes[cc - 1] + o);
        float2 a = __half22float2(p2[0]);
        float2 b = __half22float2(p2[1]);
        s.x += a.x; s.y += a.y; s.z += b.x; s.w += b.y;
    }
    s.x *= inv; s.y *= inv; s.z *= inv; s.w *= inv;
    *(float4*)(out + o) = s;
}

// ---------- threefry2x32, JAX PARTITIONABLE variant ----------
__device__ __forceinline__ uint32_t rotl32(uint32_t x, int d) { return (x << d) | (x >> (32 - d)); }

__device__ __forceinline__ bool keep_bit(uint32_t flat) {
    uint32_t x0 = 0u;
    uint32_t x1 = flat;
    const uint32_t ks0 = 0u, ks1 = 42u, ks2 = 0u ^ 42u ^ 0x1BD11BDAu;
    x0 += ks0; x1 += ks1;
#define TFR(r) { x0 += x1; x1 = rotl32(x1, r); x1 ^= x0; }
    TFR(13) TFR(15) TFR(26) TFR(6)   x0 += ks1; x1 += ks2 + 1u;
    TFR(17) TFR(29) TFR(16) TFR(24)  x0 += ks2; x1 += ks0 + 2u;
    TFR(13) TFR(15) TFR(26) TFR(6)   x0 += ks0; x1 += ks1 + 3u;
    TFR(17) TFR(29) TFR(16) TFR(24)  x0 += ks1; x1 += ks2 + 4u;
    TFR(13) TFR(15) TFR(26) TFR(6)   x0 += ks2; x1 += ks0 + 5u;
#undef TFR
    uint32_t bits = x0 ^ x1;
    float u = __uint_as_float((bits >> 9) | 0x3f800000u) - 1.0f;
    return u < 0.9f;
}

// ---------- single-sweep deferred softmax: P' = keep * exp(S) (M=0), L[row] = sum(exp) ----------
__global__ __launch_bounds__(256) void softdrop_k(__half* __restrict__ SP,
                                                  float* __restrict__ L, int N) {
    const int i = blockIdx.x;
    const int tid = threadIdx.x;
    const int len = i + 1;
    __half* row = SP + (size_t)i * N;

    float l = 0.f;
    const int len8 = len & ~7;
    for (int j = tid * 8; j < len8; j += 2048) {
        int4 pk = *(const int4*)(row + j);
        const __half* hp = (const __half*)&pk;
        __half o8[8];
        const uint32_t base = (uint32_t)i * 4096u + (uint32_t)j;
#pragma unroll
        for (int q = 0; q < 8; ++q) {
            float e = __expf(__half2float(hp[q]));
            l += e;
            o8[q] = keep_bit(base + q) ? __float2half(e) : __float2half(0.0f);
        }
        *(int4*)(row + j) = *(int4*)o8;
    }
    for (int j = len8 + tid; j < len; j += 256) {
        float e = __expf(__half2float(row[j]));
        l += e;
        row[j] = keep_bit((uint32_t)i * 4096u + (uint32_t)j) ? __float2half(e) : __float2half(0.0f);
    }

    for (int off = 1; off < 64; off <<= 1) l += __shfl_xor(l, off);
    __shared__ float ls[4];
    if ((tid & 63) == 0) ls[tid >> 6] = l;
    __syncthreads();
    if (tid == 0) L[i] = ls[0] + ls[1] + ls[2] + ls[3];

    // zero the diagonal band up to the next 256 boundary (PV K-tiles are 256 wide)
    const int zlim = ((i >> 8) << 8) + 256;
    const int za = (len + 7) & ~7;
    for (int j = len + tid; j < min(za, zlim); j += 256) row[j] = __float2half(0.0f);
    const int4 z = {0, 0, 0, 0};
    for (int j = za + tid * 8; j < zlim; j += 2048) *(int4*)(row + j) = z;
}

// ---------- launch ----------
extern "C" void kernel_launch(void* const* d_in, const int* in_sizes, int n_in,
                              void* d_out, int out_size, void* d_ws, size_t ws_size,
                              hipStream_t stream) {
    const float* x  = (const float*)d_in[0];
    const float* wq = (const float*)d_in[1];
    const float* wk = (const float*)d_in[2];
    const float* wv = (const float*)d_in[3];
    float* out = (float*)d_out;
    char* ws = (char*)d_ws;

    const int N = 4096;

    __half* xb   = (__half*)(ws + 0);          // 4096x1024   (8 MB)
    __half* wqkv = (__half*)(ws + 8388608);    // 3072x1024   (6 MB)
    __half* QK   = (__half*)(ws + 14680064);   // 4096x2048   (16 MB), ld=2048
    __half* VT   = (__half*)(ws + 31457280);   // 1024x4096   (8 MB),  ld=4096
    __half* SP   = (__half*)(ws + 48234496);   // 4096x4096   (32 MB)
    float*  Lr   = (float*)(ws + 81788928);    // 4096 f32    (16 KB)
    __half* PH1  = (__half*)(ws + 83886080);   // 4096x1024 f16 (8 MB)
    __half* PH2  = (__half*)(ws + 92274688);
    __half* PH3  = (__half*)(ws + 100663296);
    __half* PH4  = (__half*)(ws + 109051904);  // end 117440512

    __half* Q = QK;             // ld = 2048
    __half* K = QK + 1024;

    auto* g0 = gemm256<0>;
    auto* g1 = gemm256<1>;
    auto* g2 = gemm256<2>;
    (void)hipFuncSetAttribute((const void*)g0, hipFuncAttributeMaxDynamicSharedMemorySize, 131072);
    (void)hipFuncSetAttribute((const void*)g1, hipFuncAttributeMaxDynamicSharedMemorySize, 131072);
    (void)hipFuncSetAttribute((const void*)g2, hipFuncAttributeMaxDynamicSharedMemorySize, 131072);

    cast_all_k<<<3584, 256, 0, stream>>>(x, wq, wk, wv, xb, wqkv);

    // QK projection + native V^T (= wv @ x^T), one dispatch, 192 blocks
    g0<<<192, 512, 131072, stream>>>(xb, wqkv, QK, VT, nullptr, nullptr, nullptr, nullptr, nullptr);

    // S = Q @ K^T * (1/32), triangular 136 blocks
    g1<<<136, 512, 131072, stream>>>(Q, K, SP, nullptr, nullptr, nullptr, nullptr, nullptr, nullptr);

    // single sweep: P' = keep * exp(S), L[row] = sum exp(S)
    softdrop_k<<<N, 256, 0, stream>>>(SP, Lr, N);

    // PV: balanced causal split-K, 196 blocks (chunks <= 13 tiles, f16 partials)
    g2<<<196, 512, 131072, stream>>>(SP, VT, out, nullptr, PH1, PH2, PH3, PH4, Lr);

    // merge partials + apply 1/(0.9*L) for rows >= 768
    pv_merge_k<<<3328, 256, 0, stream>>>(out, PH1, PH2, PH3, PH4, Lr);
}